// Round 4
// baseline (1244.991 us; speedup 1.0000x reference)
//
#include <hip/hip_runtime.h>
#include <hip/hip_fp16.h>

#define F_IN   128
#define F_HID  16
#define NPB    2048          // nodes per bucket
#define NPB_SH 11
#define SRC_BITS 19
#define SRC_MASK 0x7FFFFu
#define ACC_STRIDE 16        // fp32 feats per node in LDS acc (128 KB total)

// ---------------- bucket histogram (dst >> 11) ----------------
__global__ __launch_bounds__(256) void k_hist1(const int* __restrict__ dst,
                                               unsigned* __restrict__ bcnt, int E) {
    __shared__ unsigned h[256];
    h[threadIdx.x] = 0;
    __syncthreads();
    for (int i = blockIdx.x * 256 + threadIdx.x; i < E; i += gridDim.x * 256)
        atomicAdd(&h[((unsigned)dst[i]) >> NPB_SH], 1u);
    __syncthreads();
    if (h[threadIdx.x]) atomicAdd(&bcnt[threadIdx.x], h[threadIdx.x]);
}

// ---------------- scan 256 bucket counts ----------------
__global__ __launch_bounds__(256) void k_scanb(const unsigned* __restrict__ bcnt,
                                               unsigned* __restrict__ bbase,
                                               unsigned* __restrict__ bfill) {
    __shared__ unsigned s[256];
    unsigned v = bcnt[threadIdx.x];
    s[threadIdx.x] = v;
    __syncthreads();
    for (int off = 1; off < 256; off <<= 1) {
        unsigned t = (threadIdx.x >= (unsigned)off) ? s[threadIdx.x - off] : 0u;
        __syncthreads();
        s[threadIdx.x] += t;
        __syncthreads();
    }
    unsigned incl = s[threadIdx.x];
    bbase[threadIdx.x + 1] = incl;
    bfill[threadIdx.x] = incl - v;    // exclusive
    if (threadIdx.x == 0) bbase[0] = 0;
}

// ---------------- bin edges into buckets (packed (ldst<<19)|src) ----------------
__global__ __launch_bounds__(1024) void k_bin(const int* __restrict__ src,
                                              const int* __restrict__ dst,
                                              unsigned* __restrict__ bfill,
                                              unsigned* __restrict__ binned, int E) {
    __shared__ unsigned hist[256], fill2[256], runbase[256];
    if (threadIdx.x < 256) { hist[threadIdx.x] = 0; fill2[threadIdx.x] = 0; }
    __syncthreads();
    unsigned val[8]; unsigned bkt[8]; bool ok[8];
    int base = blockIdx.x * 8192;
#pragma unroll
    for (int k = 0; k < 8; k++) {
        int e = base + k * 1024 + threadIdx.x;
        ok[k] = e < E;
        if (ok[k]) {
            unsigned d = (unsigned)dst[e];
            unsigned s = (unsigned)src[e];
            bkt[k] = d >> NPB_SH;
            val[k] = ((d & (NPB - 1)) << SRC_BITS) | s;
            atomicAdd(&hist[bkt[k]], 1u);
        }
    }
    __syncthreads();
    if (threadIdx.x < 256 && hist[threadIdx.x])
        runbase[threadIdx.x] = atomicAdd(&bfill[threadIdx.x], hist[threadIdx.x]);
    __syncthreads();
#pragma unroll
    for (int k = 0; k < 8; k++) {
        if (ok[k]) {
            unsigned pos = runbase[bkt[k]] + atomicAdd(&fill2[bkt[k]], 1u);
            binned[pos] = val[k];
        }
    }
}

// ---------------- per-bucket degree -> dinv (replaces k_bucket's first pass) ----------------
__global__ __launch_bounds__(1024) void k_deg(const unsigned* __restrict__ binned,
                                              const unsigned* __restrict__ bbase,
                                              float* __restrict__ dinv, int n) {
    __shared__ unsigned cnt[NPB];
    int b = blockIdx.x;
    unsigned estart = bbase[b], eend = bbase[b + 1];
    cnt[threadIdx.x] = 0; cnt[threadIdx.x + 1024] = 0;
    __syncthreads();
    for (unsigned i = estart + threadIdx.x; i < eend; i += 1024)
        atomicAdd(&cnt[binned[i] >> SRC_BITS], 1u);
    __syncthreads();
    int g0 = b * NPB + threadIdx.x;
    int g1 = g0 + 1024;
    if (g0 < n) dinv[g0] = rsqrtf((float)cnt[threadIdx.x] + 1.0f);
    if (g1 < n) dinv[g1] = rsqrtf((float)cnt[threadIdx.x + 1024] + 1.0f);
}

// ---------------- h1' = fp16( dinv .* (x @ W1) )  (LDS-staged + reg dbuf) ----------------
#define KC 32
#define XS_STRIDE 36
__global__ __launch_bounds__(256) void k_gemm1(const float* __restrict__ x,
                                               const float* __restrict__ W1,
                                               const float* __restrict__ dinv,
                                               __half* __restrict__ h1, int n) {
    __shared__ float Ws[F_IN * F_HID];          // 8 KB
    __shared__ float xs[256 * XS_STRIDE];       // 36 KB
    for (int i = threadIdx.x; i < F_IN * F_HID; i += 256) Ws[i] = W1[i];
    int t = threadIdx.x;
    int node0 = blockIdx.x * 256;
    bool active = (node0 + t) < n;
    float acc[F_HID];
#pragma unroll
    for (int c = 0; c < F_HID; c++) acc[c] = 0.f;

    float4 rbuf[8];
    auto loadc = [&](int c) {
#pragma unroll
        for (int i2 = 0; i2 < 8; i2++) {
            int f = t + i2 * 256;                // float4 index 0..2047
            int r = f >> 3;                      // staged row 0..255
            int j4 = f & 7;                      // float4 within chunk
            int gn = node0 + r;
            rbuf[i2] = (gn < n)
                ? *(const float4*)(x + (size_t)gn * F_IN + c * KC + j4 * 4)
                : make_float4(0.f, 0.f, 0.f, 0.f);
        }
    };
    loadc(0);
    for (int c = 0; c < F_IN / KC; c++) {       // 4 K-chunks
        __syncthreads();                         // xs free to overwrite (orders Ws on c==0)
#pragma unroll
        for (int i2 = 0; i2 < 8; i2++) {
            int f = t + i2 * 256;
            int r = f >> 3;
            int j4 = f & 7;
            *(float4*)(xs + r * XS_STRIDE + j4 * 4) = rbuf[i2];
        }
        __syncthreads();                         // xs ready
        if (c + 1 < F_IN / KC) loadc(c + 1);     // in-flight during compute below
        if (active) {
#pragma unroll
            for (int j4 = 0; j4 < 8; j4++) {
                float4 p = *(const float4*)(xs + t * XS_STRIDE + j4 * 4);
                int kk = c * KC + j4 * 4;
                const float* w0 = &Ws[(kk + 0) * F_HID];
                const float* w1 = &Ws[(kk + 1) * F_HID];
                const float* w2 = &Ws[(kk + 2) * F_HID];
                const float* w3 = &Ws[(kk + 3) * F_HID];
#pragma unroll
                for (int cc = 0; cc < F_HID; cc++)
                    acc[cc] += p.x * w0[cc] + p.y * w1[cc] + p.z * w2[cc] + p.w * w3[cc];
            }
        }
    }
    if (!active) return;
    float di = dinv[node0 + t];
    __half2 hv[8];
#pragma unroll
    for (int q = 0; q < 8; q++)
        hv[q] = __floats2half2_rn(acc[2 * q] * di, acc[2 * q + 1] * di);
    uint4* out = (uint4*)(h1 + (size_t)(node0 + t) * F_HID);   // 32B/node
    out[0] = *(uint4*)&hv[0];
    out[1] = *(uint4*)&hv[4];
}

// ---- layer-1 fused aggregate over binned (no CSR): LDS acc[2048][16] fp32 ----
// One block per dst-bucket. 64 16-lane groups stream the bucket's edges
// (chunked-contiguous per group, unroll 8 => 8 gathers in flight), gather
// h1'[src] rows (fp16, 32B) and ds_add_f32 into acc[ldst][lane].
// Stride 16 floats => at most 2-way bank aliasing across a wave (free, m136).
// Epilogue folds self-loop + b1 + ReLU + W2 -> h2' = dinv * (.@W2).
__global__ __launch_bounds__(1024) void k_aggf1(const unsigned* __restrict__ binned,
                                                const unsigned* __restrict__ bbase,
                                                const float* __restrict__ dinv,
                                                const __half* __restrict__ h1,
                                                const float* __restrict__ b1,
                                                const float* __restrict__ W2,
                                                float2* __restrict__ h2, int n) {
    __shared__ float acc[NPB * ACC_STRIDE];     // 128 KB
    int b = blockIdx.x;
    unsigned estart = bbase[b], eend = bbase[b + 1];
    float4* az = (float4*)acc;
    for (int i = threadIdx.x; i < NPB * ACC_STRIDE / 4; i += 1024)
        az[i] = make_float4(0.f, 0.f, 0.f, 0.f);
    __syncthreads();

    int lane = threadIdx.x & 15;
    int grp  = threadIdx.x >> 4;                // 0..63
    unsigned ecount = eend - estart;
    unsigned chunk = (ecount + 63) >> 6;
    unsigned gs = estart + (unsigned)grp * chunk;
    unsigned ge = gs + chunk;
    if (gs > eend) gs = eend;
    if (ge > eend) ge = eend;
    unsigned i = gs;
    for (; i + 8 <= ge; i += 8) {
        unsigned v0 = binned[i + 0], v1 = binned[i + 1], v2 = binned[i + 2], v3 = binned[i + 3];
        unsigned v4 = binned[i + 4], v5 = binned[i + 5], v6 = binned[i + 6], v7 = binned[i + 7];
        float f0 = __half2float(h1[(size_t)(v0 & SRC_MASK) * F_HID + lane]);
        float f1 = __half2float(h1[(size_t)(v1 & SRC_MASK) * F_HID + lane]);
        float f2 = __half2float(h1[(size_t)(v2 & SRC_MASK) * F_HID + lane]);
        float f3 = __half2float(h1[(size_t)(v3 & SRC_MASK) * F_HID + lane]);
        float f4 = __half2float(h1[(size_t)(v4 & SRC_MASK) * F_HID + lane]);
        float f5 = __half2float(h1[(size_t)(v5 & SRC_MASK) * F_HID + lane]);
        float f6 = __half2float(h1[(size_t)(v6 & SRC_MASK) * F_HID + lane]);
        float f7 = __half2float(h1[(size_t)(v7 & SRC_MASK) * F_HID + lane]);
        atomicAdd(&acc[(v0 >> SRC_BITS) * ACC_STRIDE + lane], f0);
        atomicAdd(&acc[(v1 >> SRC_BITS) * ACC_STRIDE + lane], f1);
        atomicAdd(&acc[(v2 >> SRC_BITS) * ACC_STRIDE + lane], f2);
        atomicAdd(&acc[(v3 >> SRC_BITS) * ACC_STRIDE + lane], f3);
        atomicAdd(&acc[(v4 >> SRC_BITS) * ACC_STRIDE + lane], f4);
        atomicAdd(&acc[(v5 >> SRC_BITS) * ACC_STRIDE + lane], f5);
        atomicAdd(&acc[(v6 >> SRC_BITS) * ACC_STRIDE + lane], f6);
        atomicAdd(&acc[(v7 >> SRC_BITS) * ACC_STRIDE + lane], f7);
    }
    for (; i < ge; ++i) {
        unsigned v = binned[i];
        float f = __half2float(h1[(size_t)(v & SRC_MASK) * F_HID + lane]);
        atomicAdd(&acc[(v >> SRC_BITS) * ACC_STRIDE + lane], f);
    }
    __syncthreads();

    // epilogue: 2 nodes per thread, coalesced over node index
#pragma unroll
    for (int q = 0; q < 2; q++) {
        int ld = threadIdx.x + q * 1024;
        int g = b * NPB + ld;
        if (g < n) {
            float di = dinv[g];
            const __half* hs = h1 + (size_t)g * F_HID;
            float c0 = 0.f, c1 = 0.f;
#pragma unroll
            for (int f = 0; f < F_HID; f++) {
                float s = acc[ld * ACC_STRIDE + f] + __half2float(hs[f]);
                s = s * di + b1[f];
                float v = fmaxf(s, 0.f);
                c0 += v * W2[f * 2 + 0];
                c1 += v * W2[f * 2 + 1];
            }
            h2[g] = make_float2(c0 * di, c1 * di);   // h2' = dinv * h2
        }
    }
}

// ---- layer-2 fused aggregate over binned: LDS acc[2048][2] + log_softmax ----
__global__ __launch_bounds__(1024) void k_aggf2(const unsigned* __restrict__ binned,
                                                const unsigned* __restrict__ bbase,
                                                const float* __restrict__ dinv,
                                                const float2* __restrict__ h2,
                                                const float* __restrict__ b2,
                                                float2* __restrict__ out, int n) {
    __shared__ float acc[NPB * 2];              // 16 KB
    int b = blockIdx.x;
    unsigned estart = bbase[b], eend = bbase[b + 1];
    float4* az = (float4*)acc;
    for (int i = threadIdx.x; i < NPB * 2 / 4; i += 1024)
        az[i] = make_float4(0.f, 0.f, 0.f, 0.f);
    __syncthreads();

    unsigned i = estart + threadIdx.x;
    for (; i + 3072 < eend; i += 4096) {
        unsigned v0 = binned[i], v1 = binned[i + 1024], v2 = binned[i + 2048], v3 = binned[i + 3072];
        float2 g0 = h2[v0 & SRC_MASK];
        float2 g1 = h2[v1 & SRC_MASK];
        float2 g2 = h2[v2 & SRC_MASK];
        float2 g3 = h2[v3 & SRC_MASK];
        atomicAdd(&acc[(v0 >> SRC_BITS) * 2 + 0], g0.x);
        atomicAdd(&acc[(v0 >> SRC_BITS) * 2 + 1], g0.y);
        atomicAdd(&acc[(v1 >> SRC_BITS) * 2 + 0], g1.x);
        atomicAdd(&acc[(v1 >> SRC_BITS) * 2 + 1], g1.y);
        atomicAdd(&acc[(v2 >> SRC_BITS) * 2 + 0], g2.x);
        atomicAdd(&acc[(v2 >> SRC_BITS) * 2 + 1], g2.y);
        atomicAdd(&acc[(v3 >> SRC_BITS) * 2 + 0], g3.x);
        atomicAdd(&acc[(v3 >> SRC_BITS) * 2 + 1], g3.y);
    }
    for (; i < eend; i += 1024) {
        unsigned v = binned[i];
        float2 gv = h2[v & SRC_MASK];
        atomicAdd(&acc[(v >> SRC_BITS) * 2 + 0], gv.x);
        atomicAdd(&acc[(v >> SRC_BITS) * 2 + 1], gv.y);
    }
    __syncthreads();

#pragma unroll
    for (int q = 0; q < 2; q++) {
        int ld = threadIdx.x + q * 1024;
        int g = b * NPB + ld;
        if (g < n) {
            float di = dinv[g];
            float2 hs = h2[g];
            float v0 = (acc[ld * 2 + 0] + hs.x) * di + b2[0];
            float v1 = (acc[ld * 2 + 1] + hs.y) * di + b2[1];
            float m = fmaxf(v0, v1);
            float lse = m + log1pf(expf(fminf(v0, v1) - m));
            out[g] = make_float2(v0 - lse, v1 - lse);
        }
    }
}

extern "C" void kernel_launch(void* const* d_in, const int* in_sizes, int n_in,
                              void* d_out, int out_size, void* d_ws, size_t ws_size,
                              hipStream_t stream) {
    const float* x  = (const float*)d_in[0];
    const int*   ei = (const int*)d_in[1];
    const float* W1 = (const float*)d_in[2];
    const float* b1 = (const float*)d_in[3];
    const float* W2 = (const float*)d_in[4];
    const float* b2 = (const float*)d_in[5];

    int n = in_sizes[0] / F_IN;   // 500000
    int E = in_sizes[1] / 2;      // 8000000
    const int* src = ei;
    const int* dst = ei + E;
    int B = (n + NPB - 1) / NPB;  // 245 buckets

    // workspace layout (binned persists through aggf2 now; h1 separate)
    char* ws = (char*)d_ws;
    size_t off = 0;
    auto alloc = [&](size_t bytes) { char* p = ws + off; off = (off + bytes + 63) & ~size_t(63); return p; };
    float*    dinv    = (float*)alloc(4 * (size_t)n);
    unsigned* bcnt    = (unsigned*)alloc(1024);
    unsigned* bbase   = (unsigned*)alloc(1028);
    unsigned* bfill   = (unsigned*)alloc(1024);
    unsigned* binned  = (unsigned*)alloc(4 * (size_t)E);   // 32 MB
    __half*   h1      = (__half*)alloc(2 * (size_t)n * F_HID);  // 16 MB
    float2*   h2      = (float2*)alloc(8 * (size_t)n);     // 4 MB

    int bN = (n + 255) / 256;
    int bBIN = (E + 8191) / 8192;

    hipMemsetAsync(bcnt, 0, 1024, stream);
    k_hist1 <<<1024, 256, 0, stream>>>(dst, bcnt, E);
    k_scanb <<<1, 256, 0, stream>>>(bcnt, bbase, bfill);
    k_bin   <<<bBIN, 1024, 0, stream>>>(src, dst, bfill, binned, E);
    k_deg   <<<B, 1024, 0, stream>>>(binned, bbase, dinv, n);
    k_gemm1 <<<bN, 256, 0, stream>>>(x, W1, dinv, h1, n);
    k_aggf1 <<<B, 1024, 0, stream>>>(binned, bbase, dinv, h1, b1, W2, h2, n);
    k_aggf2 <<<B, 1024, 0, stream>>>(binned, bbase, dinv, h2, b2, (float2*)d_out, n);
}